// Round 9
// baseline (57.301 us; speedup 1.0000x reference)
//
#include <hip/hip_runtime.h>
#include <hip/hip_bf16.h>
#include <math.h>

typedef __attribute__((ext_vector_type(8))) short short8;
typedef __attribute__((ext_vector_type(4))) float f32x4;

__device__ __forceinline__ unsigned pkbf2(float lo, float hi) {
    __hip_bfloat162 h = __float22bfloat162_rn(make_float2(lo, hi));
    union { __hip_bfloat162 h; unsigned u; } c;
    c.h = h;
    return c.u;
}

// One fused kernel: 512 blocks (one per batch) x 512 threads (8 waves).
// Wave w = (row-half h = w>>2, col-group wc = w&3): 32 rows x 64 cols of h2.
// Each wave reads only its half of sA per slice (halves LDS-read traffic vs
// the 64-rows-x-32-cols mapping). Full W2 B-fragment cache: 128 VGPR.
// NOTE: __launch_bounds__(512,2) REQUIRED — (512,4) spills (R7: 54 MB FETCH).
__global__ __launch_bounds__(512, 2) void actor_kernel(
    const float* __restrict__ obs,  const float* __restrict__ obst,
    const float* __restrict__ eps,  const float* __restrict__ W1,
    const float* __restrict__ b1,   const float* __restrict__ W2,
    const float* __restrict__ b2,   const float* __restrict__ muW,
    const float* __restrict__ mub,  const float* __restrict__ lsW,
    const float* __restrict__ lsb,  float* __restrict__ out)
{
    __shared__ __align__(16) short sA[4 * 64 * 64];   // 4 pages x (64 rows x 64 j), 32 KB
    __shared__ float sVeh[256];
    __shared__ float sRed[8][4];

    const int b = blockIdx.x;
    const int t = threadIdx.x;
    const int l = t & 63;
    const int w = t >> 6;
    const int h = w >> 2;          // row half: rows [h*32, h*32+32) within each 64-row slice
    const int wc = w & 3;          // col group: cols [wc*64, wc*64+64)
    const int g = l >> 4;
    const int ln = l & 15;

    // per-batch bias vector veh@W1[:15]+b1
    if (t < 256) {
        float a = b1[t];
#pragma unroll
        for (int i = 0; i < 15; ++i) a = fmaf(obs[b * 15 + i], W1[i * 256 + t], a);
        sVeh[t] = a;
    }

    // ---- layer-2 B-fragments from W2 (f32, row-major [k][col]) ----
    // frag (kt,c): elem j = W2[kt*32 + g*8 + j][(wc*4+c)*16 + ln]
    short8 bfr[8][4];
#pragma unroll
    for (int kt = 0; kt < 8; ++kt) {
#pragma unroll
        for (int c = 0; c < 4; ++c) {
            const float* p = W2 + (size_t)(kt * 32 + g * 8) * 256 + (wc * 4 + c) * 16 + ln;
            union { short8 s; unsigned u[4]; } tv;
            tv.u[0] = pkbf2(p[0 * 256], p[1 * 256]);
            tv.u[1] = pkbf2(p[2 * 256], p[3 * 256]);
            tv.u[2] = pkbf2(p[4 * 256], p[5 * 256]);
            tv.u[3] = pkbf2(p[6 * 256], p[7 * 256]);
            bfr[kt][c] = tv.s;
        }
    }

    // ---- layer-1 A-fragments (W1obst^T, K=32 with only k<4 nonzero) ----
    short8 a1[2];
#pragma unroll
    for (int ji = 0; ji < 2; ++ji) {
        union { short8 s; unsigned u[4]; } tv;
        tv.u[0] = 0u; tv.u[1] = 0u; tv.u[2] = 0u; tv.u[3] = 0u;
        if (g == 0) {
            int j = (w * 2 + ji) * 16 + ln;
            tv.u[0] = pkbf2(W1[15 * 256 + j], W1[16 * 256 + j]);
            tv.u[1] = pkbf2(W1[17 * 256 + j], W1[18 * 256 + j]);
        }
        a1[ji] = tv.s;
    }

    // loop-invariant pooling weights for this lane's 4 cols
    float bb[4]; float2 mwv[4], lwv[4];
#pragma unroll
    for (int c = 0; c < 4; ++c) {
        int col = wc * 64 + c * 16 + ln;
        bb[c] = b2[col];
        mwv[c] = *reinterpret_cast<const float2*>(muW + col * 2);
        lwv[c] = *reinterpret_cast<const float2*>(lsW + col * 2);
    }

    const float* ob = obst + b * 1280;
    const float* maskbase = ob + 1024;

    // layer-1 B-fragments (obstacle rows, K=4 in low k-slots) for one 64-row slice
    short8 bf1[4];
    auto loadB1 = [&](int q) {
#pragma unroll
        for (int nt = 0; nt < 4; ++nt) {
            union { short8 s; unsigned u[4]; } tv;
            tv.u[0] = 0u; tv.u[1] = 0u; tv.u[2] = 0u; tv.u[3] = 0u;
            if (l < 16) {
                const float* pp = ob + q * 64 + nt * 16 + l;
                tv.u[0] = pkbf2(pp[0], pp[256]);
                tv.u[1] = pkbf2(pp[512], pp[768]);
            }
            bf1[nt] = tv.s;
        }
    };
    loadB1(0);

    f32x4 acc[2][4];
#pragma unroll
    for (int m = 0; m < 2; ++m)
#pragma unroll
        for (int c = 0; c < 4; ++c) acc[m][c] = (f32x4){0.f, 0.f, 0.f, 0.f};
    float m0 = 0.f, m1 = 0.f, s0 = 0.f, s1 = 0.f;

    __syncthreads();   // sVeh ready

    for (int q = 0; q < 4; ++q) {
        // ---- layer 1: this wave's 2 j-tiles x 4 n-tiles -> LDS ----
#pragma unroll
        for (int ji = 0; ji < 2; ++ji) {
            int jt = w * 2 + ji;
            int j0 = jt * 16 + g * 4;
            f32x4 bias = *reinterpret_cast<const f32x4*>(&sVeh[j0]);
            unsigned page = (unsigned)(j0 >> 6) * 8192;
            unsigned jbyte = (unsigned)((j0 & 63) * 2);
#pragma unroll
            for (int nt = 0; nt < 4; ++nt) {
                f32x4 d = (f32x4){0.f, 0.f, 0.f, 0.f};
                d = __builtin_amdgcn_mfma_f32_16x16x32_bf16(a1[ji], bf1[nt], d, 0, 0, 0);
                int n = nt * 16 + ln;
                uint2 u;
                u.x = pkbf2(fmaxf(d[0] + bias[0], 0.f), fmaxf(d[1] + bias[1], 0.f));
                u.y = pkbf2(fmaxf(d[2] + bias[2], 0.f), fmaxf(d[3] + bias[3], 0.f));
                unsigned off = page + (unsigned)(n * 128) + (jbyte ^ ((unsigned)((n & 7) << 4)));
                *reinterpret_cast<uint2*>((char*)sA + off) = u;
            }
        }
        if (q < 3) loadB1(q + 1);   // prefetch next slice's obstacle frags
        __syncthreads();            // h1 slice ready

        // ---- layer 2: full K; B from registers, A (this wave's 32-row half) from LDS ----
#pragma unroll
        for (int kt = 0; kt < 8; ++kt) {
            unsigned page = (unsigned)(kt >> 1) * 8192;
            unsigned kbyte = (unsigned)((kt & 1) * 64 + g * 16);
#pragma unroll
            for (int m = 0; m < 2; ++m) {
                int n = h * 32 + m * 16 + ln;
                unsigned off = page + (unsigned)(n * 128) + (kbyte ^ ((unsigned)((n & 7) << 4)));
                short8 afr = *reinterpret_cast<const short8*>((const char*)sA + off);
#pragma unroll
                for (int c = 0; c < 4; ++c)
                    acc[m][c] = __builtin_amdgcn_mfma_f32_16x16x32_bf16(afr, bfr[kt][c], acc[m][c], 0, 0, 0);
            }
        }

        // ---- masked pool of this wave's 32 rows, fused with muW/lsW dot; reset acc ----
        const float* maskp = maskbase + q * 64 + h * 32;
#pragma unroll
        for (int c = 0; c < 4; ++c) {
            float p = 0.f;
#pragma unroll
            for (int m = 0; m < 2; ++m) {
                float4 M = *reinterpret_cast<const float4*>(maskp + m * 16 + g * 4);
                f32x4 v = acc[m][c];
                p = fmaf(M.x, fmaxf(v[0] + bb[c], 0.f), p);
                p = fmaf(M.y, fmaxf(v[1] + bb[c], 0.f), p);
                p = fmaf(M.z, fmaxf(v[2] + bb[c], 0.f), p);
                p = fmaf(M.w, fmaxf(v[3] + bb[c], 0.f), p);
                acc[m][c] = (f32x4){0.f, 0.f, 0.f, 0.f};
            }
            p += __shfl_xor(p, 16);
            p += __shfl_xor(p, 32);          // all lanes: pooled partial for col
            m0 = fmaf(p, mwv[c].x, m0);
            m1 = fmaf(p, mwv[c].y, m1);
            s0 = fmaf(p, lwv[c].x, s0);
            s1 = fmaf(p, lwv[c].y, s1);
        }
        if (q < 3) __syncthreads();          // LDS reuse guard
    }

    // ---- block-level reduction + head (row halves sum via sRed) ----
#pragma unroll
    for (int off = 1; off < 16; off <<= 1) {
        m0 += __shfl_xor(m0, off);
        m1 += __shfl_xor(m1, off);
        s0 += __shfl_xor(s0, off);
        s1 += __shfl_xor(s1, off);
    }
    if (l == 0) { sRed[w][0] = m0; sRed[w][1] = m1; sRed[w][2] = s0; sRed[w][3] = s1; }
    __syncthreads();
    if (t == 0) {
        float M0 = 0.f, M1 = 0.f, S0 = 0.f, S1 = 0.f;
#pragma unroll
        for (int ww = 0; ww < 8; ++ww) {
            M0 += sRed[ww][0]; M1 += sRed[ww][1];
            S0 += sRed[ww][2]; S1 += sRed[ww][3];
        }
        float mu0 = M0 + mub[0], mu1 = M1 + mub[1];
        float ls0 = fminf(fmaxf(S0 + lsb[0], -20.f), 2.f);
        float ls1 = fminf(fmaxf(S1 + lsb[1], -20.f), 2.f);
        float e0 = eps[b * 2 + 0], e1 = eps[b * 2 + 1];
        float a0 = fmaf(expf(ls0), e0, mu0);
        float a1v = fmaf(expf(ls1), e1, mu1);
        float logp = -0.5f * (e0 * e0 + e1 * e1) - (ls0 + ls1) - 1.8378770664093453f;
        float x0 = -2.f * a0, x1 = -2.f * a1v;
        float sp0 = fmaxf(x0, 0.f) + log1pf(expf(-fabsf(x0)));
        float sp1 = fmaxf(x1, 0.f) + log1pf(expf(-fabsf(x1)));
        logp -= 2.f * (0.6931471805599453f - a0 - sp0);
        logp -= 2.f * (0.6931471805599453f - a1v - sp1);
        out[b * 2 + 0] = tanhf(a0);
        out[b * 2 + 1] = tanhf(a1v);
        out[1024 + b] = logp;
    }
}

extern "C" void kernel_launch(void* const* d_in, const int* in_sizes, int n_in,
                              void* d_out, int out_size, void* d_ws, size_t ws_size,
                              hipStream_t stream) {
    const float* obs  = (const float*)d_in[0];
    const float* obst = (const float*)d_in[1];
    const float* eps  = (const float*)d_in[2];
    const float* W1   = (const float*)d_in[3];
    const float* b1   = (const float*)d_in[4];
    const float* W2   = (const float*)d_in[5];
    const float* b2   = (const float*)d_in[6];
    const float* muW  = (const float*)d_in[7];
    const float* mub  = (const float*)d_in[8];
    const float* lsW  = (const float*)d_in[9];
    const float* lsb  = (const float*)d_in[10];
    float* out = (float*)d_out;

    actor_kernel<<<512, 512, 0, stream>>>(obs, obst, eps, W1, b1, W2, b2,
                                          muW, mub, lsW, lsb, out);
}

// Round 10
// 51.823 us; speedup vs baseline: 1.1057x; 1.1057x over previous
//
#include <hip/hip_runtime.h>
#include <hip/hip_bf16.h>
#include <math.h>

typedef __attribute__((ext_vector_type(8))) short short8;
typedef __attribute__((ext_vector_type(4))) float f32x4;

__device__ __forceinline__ unsigned pkbf2(float lo, float hi) {
    __hip_bfloat162 h = __float22bfloat162_rn(make_float2(lo, hi));
    union { __hip_bfloat162 h; unsigned u; } c;
    c.h = h;
    return c.u;
}

// One fused kernel: 512 blocks (one per batch) x 512 threads (8 waves).
// Wave w = (row-half h = w>>2, col-group wc = w&3): 32 rows x 64 cols of h2.
// Halves LDS-read traffic vs R8's 64x32 mapping. B-cache = 128 VGPR; the
// build loop is fenced with sched_barrier(0) per kt so the compiler cannot
// hoist all 256 W2 loads into flight (R9's spill: 44 MB WRITE_SIZE).
// __launch_bounds__(512,2) REQUIRED - (512,4) spills (R7).
__global__ __launch_bounds__(512, 2) void actor_kernel(
    const float* __restrict__ obs,  const float* __restrict__ obst,
    const float* __restrict__ eps,  const float* __restrict__ W1,
    const float* __restrict__ b1,   const float* __restrict__ W2,
    const float* __restrict__ b2,   const float* __restrict__ muW,
    const float* __restrict__ mub,  const float* __restrict__ lsW,
    const float* __restrict__ lsb,  float* __restrict__ out)
{
    __shared__ __align__(16) short sA[4 * 64 * 64];   // 4 pages x (64 rows x 64 j), 32 KB
    __shared__ float sVeh[256];
    __shared__ float sRed[8][4];

    const int b = blockIdx.x;
    const int t = threadIdx.x;
    const int l = t & 63;
    const int w = t >> 6;
    const int h = w >> 2;          // row half within each 64-row slice
    const int wc = w & 3;          // col group: cols [wc*64, wc*64+64)
    const int g = l >> 4;
    const int ln = l & 15;

    // per-batch bias vector veh@W1[:15]+b1
    if (t < 256) {
        float a = b1[t];
#pragma unroll
        for (int i = 0; i < 15; ++i) a = fmaf(obs[b * 15 + i], W1[i * 256 + t], a);
        sVeh[t] = a;
    }

    // ---- layer-2 B-fragments from W2 (f32, row-major [k][col]) ----
    // frag (kt,c): elem j = W2[kt*32 + g*8 + j][(wc*4+c)*16 + ln]
    short8 bfr[8][4];
#pragma unroll
    for (int kt = 0; kt < 8; ++kt) {
#pragma unroll
        for (int c = 0; c < 4; ++c) {
            const float* p = W2 + (size_t)(kt * 32 + g * 8) * 256 + (wc * 4 + c) * 16 + ln;
            union { short8 s; unsigned u[4]; } tv;
            tv.u[0] = pkbf2(p[0 * 256], p[1 * 256]);
            tv.u[1] = pkbf2(p[2 * 256], p[3 * 256]);
            tv.u[2] = pkbf2(p[4 * 256], p[5 * 256]);
            tv.u[3] = pkbf2(p[6 * 256], p[7 * 256]);
            bfr[kt][c] = tv.s;
        }
        __builtin_amdgcn_sched_barrier(0);   // cap live W2 loads at one kt batch
    }

    // ---- layer-1 A-fragments (W1obst^T, K=32 with only k<4 nonzero) ----
    short8 a1[2];
#pragma unroll
    for (int ji = 0; ji < 2; ++ji) {
        union { short8 s; unsigned u[4]; } tv;
        tv.u[0] = 0u; tv.u[1] = 0u; tv.u[2] = 0u; tv.u[3] = 0u;
        if (g == 0) {
            int j = (w * 2 + ji) * 16 + ln;
            tv.u[0] = pkbf2(W1[15 * 256 + j], W1[16 * 256 + j]);
            tv.u[1] = pkbf2(W1[17 * 256 + j], W1[18 * 256 + j]);
        }
        a1[ji] = tv.s;
    }

    // loop-invariant: only b2 bias needed inside the loop (muW/lsW dot deferred)
    float bb[4];
#pragma unroll
    for (int c = 0; c < 4; ++c) bb[c] = b2[wc * 64 + c * 16 + ln];

    const float* ob = obst + b * 1280;
    const float* maskbase = ob + 1024;

    // layer-1 B-fragments (obstacle rows, K=4 in low k-slots) for one 64-row slice
    short8 bf1[4];
    auto loadB1 = [&](int q) {
#pragma unroll
        for (int nt = 0; nt < 4; ++nt) {
            union { short8 s; unsigned u[4]; } tv;
            tv.u[0] = 0u; tv.u[1] = 0u; tv.u[2] = 0u; tv.u[3] = 0u;
            if (l < 16) {
                const float* pp = ob + q * 64 + nt * 16 + l;
                tv.u[0] = pkbf2(pp[0], pp[256]);
                tv.u[1] = pkbf2(pp[512], pp[768]);
            }
            bf1[nt] = tv.s;
        }
    };
    loadB1(0);

    f32x4 acc[2][4];
#pragma unroll
    for (int m = 0; m < 2; ++m)
#pragma unroll
        for (int c = 0; c < 4; ++c) acc[m][c] = (f32x4){0.f, 0.f, 0.f, 0.f};
    float pc[4] = {0.f, 0.f, 0.f, 0.f};     // raw pooled accumulator per col

    __syncthreads();   // sVeh ready

    for (int q = 0; q < 4; ++q) {
        // ---- layer 1: this wave's 2 j-tiles x 4 n-tiles -> LDS ----
#pragma unroll
        for (int ji = 0; ji < 2; ++ji) {
            int jt = w * 2 + ji;
            int j0 = jt * 16 + g * 4;
            f32x4 bias = *reinterpret_cast<const f32x4*>(&sVeh[j0]);
            unsigned page = (unsigned)(j0 >> 6) * 8192;
            unsigned jbyte = (unsigned)((j0 & 63) * 2);
#pragma unroll
            for (int nt = 0; nt < 4; ++nt) {
                f32x4 d = (f32x4){0.f, 0.f, 0.f, 0.f};
                d = __builtin_amdgcn_mfma_f32_16x16x32_bf16(a1[ji], bf1[nt], d, 0, 0, 0);
                int n = nt * 16 + ln;
                uint2 u;
                u.x = pkbf2(fmaxf(d[0] + bias[0], 0.f), fmaxf(d[1] + bias[1], 0.f));
                u.y = pkbf2(fmaxf(d[2] + bias[2], 0.f), fmaxf(d[3] + bias[3], 0.f));
                unsigned off = page + (unsigned)(n * 128) + (jbyte ^ ((unsigned)((n & 7) << 4)));
                *reinterpret_cast<uint2*>((char*)sA + off) = u;
            }
        }
        if (q < 3) loadB1(q + 1);   // prefetch next slice's obstacle frags
        __syncthreads();            // h1 slice ready

        // ---- layer 2: full K; B from registers, A (this wave's 32-row half) from LDS ----
#pragma unroll
        for (int kt = 0; kt < 8; ++kt) {
            unsigned page = (unsigned)(kt >> 1) * 8192;
            unsigned kbyte = (unsigned)((kt & 1) * 64 + g * 16);
#pragma unroll
            for (int m = 0; m < 2; ++m) {
                int n = h * 32 + m * 16 + ln;
                unsigned off = page + (unsigned)(n * 128) + (kbyte ^ ((unsigned)((n & 7) << 4)));
                short8 afr = *reinterpret_cast<const short8*>((const char*)sA + off);
#pragma unroll
                for (int c = 0; c < 4; ++c)
                    acc[m][c] = __builtin_amdgcn_mfma_f32_16x16x32_bf16(afr, bfr[kt][c], acc[m][c], 0, 0, 0);
            }
        }

        // ---- masked pool of this wave's 32 rows; accumulate raw pooled; reset acc ----
        const float* maskp = maskbase + q * 64 + h * 32;
#pragma unroll
        for (int c = 0; c < 4; ++c) {
            float p = 0.f;
#pragma unroll
            for (int m = 0; m < 2; ++m) {
                float4 M = *reinterpret_cast<const float4*>(maskp + m * 16 + g * 4);
                f32x4 v = acc[m][c];
                p = fmaf(M.x, fmaxf(v[0] + bb[c], 0.f), p);
                p = fmaf(M.y, fmaxf(v[1] + bb[c], 0.f), p);
                p = fmaf(M.z, fmaxf(v[2] + bb[c], 0.f), p);
                p = fmaf(M.w, fmaxf(v[3] + bb[c], 0.f), p);
                acc[m][c] = (f32x4){0.f, 0.f, 0.f, 0.f};
            }
            p += __shfl_xor(p, 16);
            p += __shfl_xor(p, 32);          // all lanes: pooled partial for col
            pc[c] += p;
        }
        if (q < 3) __syncthreads();          // LDS reuse guard
    }

    // ---- deferred muW/lsW dot, block reduction, head ----
    float m0 = 0.f, m1 = 0.f, s0 = 0.f, s1 = 0.f;
#pragma unroll
    for (int c = 0; c < 4; ++c) {
        int col = wc * 64 + c * 16 + ln;
        float2 mw = *reinterpret_cast<const float2*>(muW + col * 2);
        float2 lw = *reinterpret_cast<const float2*>(lsW + col * 2);
        m0 = fmaf(pc[c], mw.x, m0);
        m1 = fmaf(pc[c], mw.y, m1);
        s0 = fmaf(pc[c], lw.x, s0);
        s1 = fmaf(pc[c], lw.y, s1);
    }
#pragma unroll
    for (int off = 1; off < 16; off <<= 1) {
        m0 += __shfl_xor(m0, off);
        m1 += __shfl_xor(m1, off);
        s0 += __shfl_xor(s0, off);
        s1 += __shfl_xor(s1, off);
    }
    if (l == 0) { sRed[w][0] = m0; sRed[w][1] = m1; sRed[w][2] = s0; sRed[w][3] = s1; }
    __syncthreads();
    if (t == 0) {
        float M0 = 0.f, M1 = 0.f, S0 = 0.f, S1 = 0.f;
#pragma unroll
        for (int ww = 0; ww < 8; ++ww) {
            M0 += sRed[ww][0]; M1 += sRed[ww][1];
            S0 += sRed[ww][2]; S1 += sRed[ww][3];
        }
        float mu0 = M0 + mub[0], mu1 = M1 + mub[1];
        float ls0 = fminf(fmaxf(S0 + lsb[0], -20.f), 2.f);
        float ls1 = fminf(fmaxf(S1 + lsb[1], -20.f), 2.f);
        float e0 = eps[b * 2 + 0], e1 = eps[b * 2 + 1];
        float a0 = fmaf(expf(ls0), e0, mu0);
        float a1v = fmaf(expf(ls1), e1, mu1);
        float logp = -0.5f * (e0 * e0 + e1 * e1) - (ls0 + ls1) - 1.8378770664093453f;
        float x0 = -2.f * a0, x1 = -2.f * a1v;
        float sp0 = fmaxf(x0, 0.f) + log1pf(expf(-fabsf(x0)));
        float sp1 = fmaxf(x1, 0.f) + log1pf(expf(-fabsf(x1)));
        logp -= 2.f * (0.6931471805599453f - a0 - sp0);
        logp -= 2.f * (0.6931471805599453f - a1v - sp1);
        out[b * 2 + 0] = tanhf(a0);
        out[b * 2 + 1] = tanhf(a1v);
        out[1024 + b] = logp;
    }
}

extern "C" void kernel_launch(void* const* d_in, const int* in_sizes, int n_in,
                              void* d_out, int out_size, void* d_ws, size_t ws_size,
                              hipStream_t stream) {
    const float* obs  = (const float*)d_in[0];
    const float* obst = (const float*)d_in[1];
    const float* eps  = (const float*)d_in[2];
    const float* W1   = (const float*)d_in[3];
    const float* b1   = (const float*)d_in[4];
    const float* W2   = (const float*)d_in[5];
    const float* b2   = (const float*)d_in[6];
    const float* muW  = (const float*)d_in[7];
    const float* mub  = (const float*)d_in[8];
    const float* lsW  = (const float*)d_in[9];
    const float* lsb  = (const float*)d_in[10];
    float* out = (float*)d_out;

    actor_kernel<<<512, 512, 0, stream>>>(obs, obst, eps, W1, b1, W2, b2,
                                          muW, mub, lsW, lsb, out);
}

// Round 11
// 51.729 us; speedup vs baseline: 1.1077x; 1.0018x over previous
//
#include <hip/hip_runtime.h>
#include <hip/hip_bf16.h>
#include <math.h>

typedef __attribute__((ext_vector_type(8))) short short8;
typedef __attribute__((ext_vector_type(4))) float f32x4;

__device__ __forceinline__ unsigned pkbf2(float lo, float hi) {
    __hip_bfloat162 h = __float22bfloat162_rn(make_float2(lo, hi));
    union { __hip_bfloat162 h; unsigned u; } c;
    c.h = h;
    return c.u;
}

// One fused kernel: 512 blocks (one per batch) x 512 threads (8 waves).
// Wave w = (row-half h = w>>2, col-group wc = w&3): 32 rows x 64 cols of h2.
// Halves LDS-read traffic vs R8's 64x32 mapping. B-cache = 128 VGPR.
// __launch_bounds__(512,1): R9/R10 showed (512,2) caps the allocator at 128
// VGPR (4-waves/SIMD tier) and force-spills the B-cache (44/23 MB WRITE_SIZE).
// (512,1) grants the full register file; ~220 regs -> 8 waves/CU occupancy.
__global__ __launch_bounds__(512, 1) void actor_kernel(
    const float* __restrict__ obs,  const float* __restrict__ obst,
    const float* __restrict__ eps,  const float* __restrict__ W1,
    const float* __restrict__ b1,   const float* __restrict__ W2,
    const float* __restrict__ b2,   const float* __restrict__ muW,
    const float* __restrict__ mub,  const float* __restrict__ lsW,
    const float* __restrict__ lsb,  float* __restrict__ out)
{
    __shared__ __align__(16) short sA[4 * 64 * 64];   // 4 pages x (64 rows x 64 j), 32 KB
    __shared__ float sVeh[256];
    __shared__ float sRed[8][4];

    const int b = blockIdx.x;
    const int t = threadIdx.x;
    const int l = t & 63;
    const int w = t >> 6;
    const int h = w >> 2;          // row half within each 64-row slice
    const int wc = w & 3;          // col group: cols [wc*64, wc*64+64)
    const int g = l >> 4;
    const int ln = l & 15;

    // per-batch bias vector veh@W1[:15]+b1
    if (t < 256) {
        float a = b1[t];
#pragma unroll
        for (int i = 0; i < 15; ++i) a = fmaf(obs[b * 15 + i], W1[i * 256 + t], a);
        sVeh[t] = a;
    }

    // ---- layer-2 B-fragments from W2 (f32, row-major [k][col]) ----
    // frag (kt,c): elem j = W2[kt*32 + g*8 + j][(wc*4+c)*16 + ln]
    short8 bfr[8][4];
#pragma unroll
    for (int kt = 0; kt < 8; ++kt) {
#pragma unroll
        for (int c = 0; c < 4; ++c) {
            const float* p = W2 + (size_t)(kt * 32 + g * 8) * 256 + (wc * 4 + c) * 16 + ln;
            union { short8 s; unsigned u[4]; } tv;
            tv.u[0] = pkbf2(p[0 * 256], p[1 * 256]);
            tv.u[1] = pkbf2(p[2 * 256], p[3 * 256]);
            tv.u[2] = pkbf2(p[4 * 256], p[5 * 256]);
            tv.u[3] = pkbf2(p[6 * 256], p[7 * 256]);
            bfr[kt][c] = tv.s;
        }
        __builtin_amdgcn_sched_barrier(0);   // cap live W2 loads at one kt batch
    }

    // ---- layer-1 A-fragments (W1obst^T, K=32 with only k<4 nonzero) ----
    short8 a1[2];
#pragma unroll
    for (int ji = 0; ji < 2; ++ji) {
        union { short8 s; unsigned u[4]; } tv;
        tv.u[0] = 0u; tv.u[1] = 0u; tv.u[2] = 0u; tv.u[3] = 0u;
        if (g == 0) {
            int j = (w * 2 + ji) * 16 + ln;
            tv.u[0] = pkbf2(W1[15 * 256 + j], W1[16 * 256 + j]);
            tv.u[1] = pkbf2(W1[17 * 256 + j], W1[18 * 256 + j]);
        }
        a1[ji] = tv.s;
    }

    // loop-invariant: only b2 bias needed inside the loop (muW/lsW dot deferred)
    float bb[4];
#pragma unroll
    for (int c = 0; c < 4; ++c) bb[c] = b2[wc * 64 + c * 16 + ln];

    const float* ob = obst + b * 1280;
    const float* maskbase = ob + 1024;

    // layer-1 B-fragments (obstacle rows, K=4 in low k-slots) for one 64-row slice
    short8 bf1[4];
    auto loadB1 = [&](int q) {
#pragma unroll
        for (int nt = 0; nt < 4; ++nt) {
            union { short8 s; unsigned u[4]; } tv;
            tv.u[0] = 0u; tv.u[1] = 0u; tv.u[2] = 0u; tv.u[3] = 0u;
            if (l < 16) {
                const float* pp = ob + q * 64 + nt * 16 + l;
                tv.u[0] = pkbf2(pp[0], pp[256]);
                tv.u[1] = pkbf2(pp[512], pp[768]);
            }
            bf1[nt] = tv.s;
        }
    };
    loadB1(0);

    f32x4 acc[2][4];
#pragma unroll
    for (int m = 0; m < 2; ++m)
#pragma unroll
        for (int c = 0; c < 4; ++c) acc[m][c] = (f32x4){0.f, 0.f, 0.f, 0.f};
    float pc[4] = {0.f, 0.f, 0.f, 0.f};     // raw pooled accumulator per col

    __syncthreads();   // sVeh ready

    for (int q = 0; q < 4; ++q) {
        // ---- layer 1: this wave's 2 j-tiles x 4 n-tiles -> LDS ----
#pragma unroll
        for (int ji = 0; ji < 2; ++ji) {
            int jt = w * 2 + ji;
            int j0 = jt * 16 + g * 4;
            f32x4 bias = *reinterpret_cast<const f32x4*>(&sVeh[j0]);
            unsigned page = (unsigned)(j0 >> 6) * 8192;
            unsigned jbyte = (unsigned)((j0 & 63) * 2);
#pragma unroll
            for (int nt = 0; nt < 4; ++nt) {
                f32x4 d = (f32x4){0.f, 0.f, 0.f, 0.f};
                d = __builtin_amdgcn_mfma_f32_16x16x32_bf16(a1[ji], bf1[nt], d, 0, 0, 0);
                int n = nt * 16 + ln;
                uint2 u;
                u.x = pkbf2(fmaxf(d[0] + bias[0], 0.f), fmaxf(d[1] + bias[1], 0.f));
                u.y = pkbf2(fmaxf(d[2] + bias[2], 0.f), fmaxf(d[3] + bias[3], 0.f));
                unsigned off = page + (unsigned)(n * 128) + (jbyte ^ ((unsigned)((n & 7) << 4)));
                *reinterpret_cast<uint2*>((char*)sA + off) = u;
            }
        }
        if (q < 3) loadB1(q + 1);   // prefetch next slice's obstacle frags
        __syncthreads();            // h1 slice ready

        // ---- layer 2: full K; B from registers, A (this wave's 32-row half) from LDS ----
#pragma unroll
        for (int kt = 0; kt < 8; ++kt) {
            unsigned page = (unsigned)(kt >> 1) * 8192;
            unsigned kbyte = (unsigned)((kt & 1) * 64 + g * 16);
#pragma unroll
            for (int m = 0; m < 2; ++m) {
                int n = h * 32 + m * 16 + ln;
                unsigned off = page + (unsigned)(n * 128) + (kbyte ^ ((unsigned)((n & 7) << 4)));
                short8 afr = *reinterpret_cast<const short8*>((const char*)sA + off);
#pragma unroll
                for (int c = 0; c < 4; ++c)
                    acc[m][c] = __builtin_amdgcn_mfma_f32_16x16x32_bf16(afr, bfr[kt][c], acc[m][c], 0, 0, 0);
            }
        }

        // ---- masked pool of this wave's 32 rows; accumulate raw pooled; reset acc ----
        const float* maskp = maskbase + q * 64 + h * 32;
#pragma unroll
        for (int c = 0; c < 4; ++c) {
            float p = 0.f;
#pragma unroll
            for (int m = 0; m < 2; ++m) {
                float4 M = *reinterpret_cast<const float4*>(maskp + m * 16 + g * 4);
                f32x4 v = acc[m][c];
                p = fmaf(M.x, fmaxf(v[0] + bb[c], 0.f), p);
                p = fmaf(M.y, fmaxf(v[1] + bb[c], 0.f), p);
                p = fmaf(M.z, fmaxf(v[2] + bb[c], 0.f), p);
                p = fmaf(M.w, fmaxf(v[3] + bb[c], 0.f), p);
                acc[m][c] = (f32x4){0.f, 0.f, 0.f, 0.f};
            }
            p += __shfl_xor(p, 16);
            p += __shfl_xor(p, 32);          // all lanes: pooled partial for col
            pc[c] += p;
        }
        if (q < 3) __syncthreads();          // LDS reuse guard
    }

    // ---- deferred muW/lsW dot, block reduction, head ----
    float m0 = 0.f, m1 = 0.f, s0 = 0.f, s1 = 0.f;
#pragma unroll
    for (int c = 0; c < 4; ++c) {
        int col = wc * 64 + c * 16 + ln;
        float2 mw = *reinterpret_cast<const float2*>(muW + col * 2);
        float2 lw = *reinterpret_cast<const float2*>(lsW + col * 2);
        m0 = fmaf(pc[c], mw.x, m0);
        m1 = fmaf(pc[c], mw.y, m1);
        s0 = fmaf(pc[c], lw.x, s0);
        s1 = fmaf(pc[c], lw.y, s1);
    }
#pragma unroll
    for (int off = 1; off < 16; off <<= 1) {
        m0 += __shfl_xor(m0, off);
        m1 += __shfl_xor(m1, off);
        s0 += __shfl_xor(s0, off);
        s1 += __shfl_xor(s1, off);
    }
    if (l == 0) { sRed[w][0] = m0; sRed[w][1] = m1; sRed[w][2] = s0; sRed[w][3] = s1; }
    __syncthreads();
    if (t == 0) {
        float M0 = 0.f, M1 = 0.f, S0 = 0.f, S1 = 0.f;
#pragma unroll
        for (int ww = 0; ww < 8; ++ww) {
            M0 += sRed[ww][0]; M1 += sRed[ww][1];
            S0 += sRed[ww][2]; S1 += sRed[ww][3];
        }
        float mu0 = M0 + mub[0], mu1 = M1 + mub[1];
        float ls0 = fminf(fmaxf(S0 + lsb[0], -20.f), 2.f);
        float ls1 = fminf(fmaxf(S1 + lsb[1], -20.f), 2.f);
        float e0 = eps[b * 2 + 0], e1 = eps[b * 2 + 1];
        float a0 = fmaf(expf(ls0), e0, mu0);
        float a1v = fmaf(expf(ls1), e1, mu1);
        float logp = -0.5f * (e0 * e0 + e1 * e1) - (ls0 + ls1) - 1.8378770664093453f;
        float x0 = -2.f * a0, x1 = -2.f * a1v;
        float sp0 = fmaxf(x0, 0.f) + log1pf(expf(-fabsf(x0)));
        float sp1 = fmaxf(x1, 0.f) + log1pf(expf(-fabsf(x1)));
        logp -= 2.f * (0.6931471805599453f - a0 - sp0);
        logp -= 2.f * (0.6931471805599453f - a1v - sp1);
        out[b * 2 + 0] = tanhf(a0);
        out[b * 2 + 1] = tanhf(a1v);
        out[1024 + b] = logp;
    }
}

extern "C" void kernel_launch(void* const* d_in, const int* in_sizes, int n_in,
                              void* d_out, int out_size, void* d_ws, size_t ws_size,
                              hipStream_t stream) {
    const float* obs  = (const float*)d_in[0];
    const float* obst = (const float*)d_in[1];
    const float* eps  = (const float*)d_in[2];
    const float* W1   = (const float*)d_in[3];
    const float* b1   = (const float*)d_in[4];
    const float* W2   = (const float*)d_in[5];
    const float* b2   = (const float*)d_in[6];
    const float* muW  = (const float*)d_in[7];
    const float* mub  = (const float*)d_in[8];
    const float* lsW  = (const float*)d_in[9];
    const float* lsb  = (const float*)d_in[10];
    float* out = (float*)d_out;

    actor_kernel<<<512, 512, 0, stream>>>(obs, obst, eps, W1, b1, W2, b2,
                                          muW, mub, lsW, lsb, out);
}

// Round 12
// 35.352 us; speedup vs baseline: 1.6209x; 1.4633x over previous
//
#include <hip/hip_runtime.h>
#include <hip/hip_bf16.h>
#include <math.h>

typedef __attribute__((ext_vector_type(8))) short short8;
typedef __attribute__((ext_vector_type(4))) float f32x4;

__device__ __forceinline__ unsigned pkbf2(float lo, float hi) {
    __hip_bfloat162 h = __float22bfloat162_rn(make_float2(lo, hi));
    union { __hip_bfloat162 h; unsigned u; } c;
    c.h = h;
    return c.u;
}

// One fused kernel: 512 blocks (one per batch) x 512 threads (8 waves).
// Wave w owns output cols [w*32, w*32+32) (R8 geometry, 84 VGPR, fits the
// 128-reg tier; the 64-col/wave variant needs 200+ regs and ALWAYS spills —
// R9/R10/R11). New in R12: double-buffered h1 slices — layer1(q+1) is
// computed into buf^1 while layer2(q) consumes buf^0; one barrier per slice
// instead of two, layer-1 VALU hides under layer-2 LDS reads.
__global__ __launch_bounds__(512, 2) void actor_kernel(
    const float* __restrict__ obs,  const float* __restrict__ obst,
    const float* __restrict__ eps,  const float* __restrict__ W1,
    const float* __restrict__ b1,   const float* __restrict__ W2,
    const float* __restrict__ b2,   const float* __restrict__ muW,
    const float* __restrict__ mub,  const float* __restrict__ lsW,
    const float* __restrict__ lsb,  float* __restrict__ out)
{
    __shared__ __align__(16) short sA[2][4 * 64 * 64];  // 2 bufs x 32 KB
    __shared__ float sVeh[256];
    __shared__ float sRed[8][4];

    const int b = blockIdx.x;
    const int t = threadIdx.x;
    const int l = t & 63;
    const int w = t >> 6;          // wave: output cols [w*32, w*32+32)
    const int g = l >> 4;
    const int ln = l & 15;

    // per-batch bias vector veh@W1[:15]+b1
    if (t < 256) {
        float a = b1[t];
#pragma unroll
        for (int i = 0; i < 15; ++i) a = fmaf(obs[b * 15 + i], W1[i * 256 + t], a);
        sVeh[t] = a;
    }

    // ---- layer-2 B-fragments from W2 (f32, row-major [k][col]) ----
    short8 bfr[8][2];
#pragma unroll
    for (int kt = 0; kt < 8; ++kt) {
#pragma unroll
        for (int c = 0; c < 2; ++c) {
            const float* p = W2 + (size_t)(kt * 32 + g * 8) * 256 + (w * 2 + c) * 16 + ln;
            union { short8 s; unsigned u[4]; } tv;
            tv.u[0] = pkbf2(p[0 * 256], p[1 * 256]);
            tv.u[1] = pkbf2(p[2 * 256], p[3 * 256]);
            tv.u[2] = pkbf2(p[4 * 256], p[5 * 256]);
            tv.u[3] = pkbf2(p[6 * 256], p[7 * 256]);
            bfr[kt][c] = tv.s;
        }
    }

    // ---- layer-1 A-fragments (W1obst^T, K=32 with only k<4 nonzero) ----
    short8 a1[2];
#pragma unroll
    for (int ji = 0; ji < 2; ++ji) {
        union { short8 s; unsigned u[4]; } tv;
        tv.u[0] = 0u; tv.u[1] = 0u; tv.u[2] = 0u; tv.u[3] = 0u;
        if (g == 0) {
            int j = (w * 2 + ji) * 16 + ln;
            tv.u[0] = pkbf2(W1[15 * 256 + j], W1[16 * 256 + j]);
            tv.u[1] = pkbf2(W1[17 * 256 + j], W1[18 * 256 + j]);
        }
        a1[ji] = tv.s;
    }

    // loop-invariant pooling weights for this lane's 2 cols
    float bb[2]; float2 mwv[2], lwv[2];
#pragma unroll
    for (int c = 0; c < 2; ++c) {
        int col = w * 32 + c * 16 + ln;
        bb[c] = b2[col];
        mwv[c] = *reinterpret_cast<const float2*>(muW + col * 2);
        lwv[c] = *reinterpret_cast<const float2*>(lsW + col * 2);
    }

    const float* ob = obst + b * 1280;
    const float* maskbase = ob + 1024;

    short8 bf1[4];
    auto loadB1 = [&](int q) {
#pragma unroll
        for (int nt = 0; nt < 4; ++nt) {
            union { short8 s; unsigned u[4]; } tv;
            tv.u[0] = 0u; tv.u[1] = 0u; tv.u[2] = 0u; tv.u[3] = 0u;
            if (l < 16) {
                const float* pp = ob + q * 64 + nt * 16 + l;
                tv.u[0] = pkbf2(pp[0], pp[256]);
                tv.u[1] = pkbf2(pp[512], pp[768]);
            }
            bf1[nt] = tv.s;
        }
    };

    // layer-1 of one 64-row slice -> sA[buf] (this wave's 2 j-tiles x 4 n-tiles)
    auto layer1 = [&](int buf) {
        char* base = (char*)&sA[buf][0];
#pragma unroll
        for (int ji = 0; ji < 2; ++ji) {
            int jt = w * 2 + ji;
            int j0 = jt * 16 + g * 4;
            f32x4 bias = *reinterpret_cast<const f32x4*>(&sVeh[j0]);
            unsigned page = (unsigned)(j0 >> 6) * 8192;
            unsigned jbyte = (unsigned)((j0 & 63) * 2);
#pragma unroll
            for (int nt = 0; nt < 4; ++nt) {
                f32x4 d = (f32x4){0.f, 0.f, 0.f, 0.f};
                d = __builtin_amdgcn_mfma_f32_16x16x32_bf16(a1[ji], bf1[nt], d, 0, 0, 0);
                int n = nt * 16 + ln;
                uint2 u;
                u.x = pkbf2(fmaxf(d[0] + bias[0], 0.f), fmaxf(d[1] + bias[1], 0.f));
                u.y = pkbf2(fmaxf(d[2] + bias[2], 0.f), fmaxf(d[3] + bias[3], 0.f));
                unsigned off = page + (unsigned)(n * 128) + (jbyte ^ ((unsigned)((n & 7) << 4)));
                *reinterpret_cast<uint2*>(base + off) = u;
            }
        }
    };

    f32x4 acc[4][2];
#pragma unroll
    for (int m = 0; m < 4; ++m)
#pragma unroll
        for (int c = 0; c < 2; ++c) acc[m][c] = (f32x4){0.f, 0.f, 0.f, 0.f};
    float m0 = 0.f, m1 = 0.f, s0 = 0.f, s1 = 0.f;

    loadB1(0);
    __syncthreads();            // sVeh ready
    layer1(0);                  // slice 0 -> buf 0
    loadB1(1);
    __syncthreads();            // buf 0 ready

    for (int q = 0; q < 4; ++q) {
        int buf = q & 1;
        // ---- produce next slice into the other buffer (overlaps layer2 below) ----
        if (q < 3) layer1(buf ^ 1);
        if (q < 2) loadB1(q + 2);

        // ---- layer 2: full K; B from registers, A from LDS buf ----
        const char* rbase = (const char*)&sA[buf][0];
#pragma unroll
        for (int kt = 0; kt < 8; ++kt) {
            unsigned page = (unsigned)(kt >> 1) * 8192;
            unsigned kbyte = (unsigned)((kt & 1) * 64 + g * 16);
#pragma unroll
            for (int m = 0; m < 4; ++m) {
                int n = m * 16 + ln;
                unsigned off = page + (unsigned)(n * 128) + (kbyte ^ ((unsigned)((n & 7) << 4)));
                short8 afr = *reinterpret_cast<const short8*>(rbase + off);
#pragma unroll
                for (int c = 0; c < 2; ++c)
                    acc[m][c] = __builtin_amdgcn_mfma_f32_16x16x32_bf16(afr, bfr[kt][c], acc[m][c], 0, 0, 0);
            }
        }

        // ---- masked pool of this slice, fused with muW/lsW dot; reset acc ----
        const float* maskp = maskbase + q * 64;
#pragma unroll
        for (int c = 0; c < 2; ++c) {
            float p = 0.f;
#pragma unroll
            for (int m = 0; m < 4; ++m) {
                float4 M = *reinterpret_cast<const float4*>(maskp + m * 16 + g * 4);
                f32x4 v = acc[m][c];
                p = fmaf(M.x, fmaxf(v[0] + bb[c], 0.f), p);
                p = fmaf(M.y, fmaxf(v[1] + bb[c], 0.f), p);
                p = fmaf(M.z, fmaxf(v[2] + bb[c], 0.f), p);
                p = fmaf(M.w, fmaxf(v[3] + bb[c], 0.f), p);
                acc[m][c] = (f32x4){0.f, 0.f, 0.f, 0.f};
            }
            p += __shfl_xor(p, 16);
            p += __shfl_xor(p, 32);          // all lanes: pooled partial for col
            m0 = fmaf(p, mwv[c].x, m0);
            m1 = fmaf(p, mwv[c].y, m1);
            s0 = fmaf(p, lwv[c].x, s0);
            s1 = fmaf(p, lwv[c].y, s1);
        }
        if (q < 3) __syncthreads();          // next buf ready / reads drained
    }

    // ---- block-level reduction + head ----
#pragma unroll
    for (int off = 1; off < 16; off <<= 1) {
        m0 += __shfl_xor(m0, off);
        m1 += __shfl_xor(m1, off);
        s0 += __shfl_xor(s0, off);
        s1 += __shfl_xor(s1, off);
    }
    if (l == 0) { sRed[w][0] = m0; sRed[w][1] = m1; sRed[w][2] = s0; sRed[w][3] = s1; }
    __syncthreads();
    if (t == 0) {
        float M0 = 0.f, M1 = 0.f, S0 = 0.f, S1 = 0.f;
#pragma unroll
        for (int ww = 0; ww < 8; ++ww) {
            M0 += sRed[ww][0]; M1 += sRed[ww][1];
            S0 += sRed[ww][2]; S1 += sRed[ww][3];
        }
        float mu0 = M0 + mub[0], mu1 = M1 + mub[1];
        float ls0 = fminf(fmaxf(S0 + lsb[0], -20.f), 2.f);
        float ls1 = fminf(fmaxf(S1 + lsb[1], -20.f), 2.f);
        float e0 = eps[b * 2 + 0], e1 = eps[b * 2 + 1];
        float a0 = fmaf(expf(ls0), e0, mu0);
        float a1v = fmaf(expf(ls1), e1, mu1);
        float logp = -0.5f * (e0 * e0 + e1 * e1) - (ls0 + ls1) - 1.8378770664093453f;
        float x0 = -2.f * a0, x1 = -2.f * a1v;
        float sp0 = fmaxf(x0, 0.f) + log1pf(expf(-fabsf(x0)));
        float sp1 = fmaxf(x1, 0.f) + log1pf(expf(-fabsf(x1)));
        logp -= 2.f * (0.6931471805599453f - a0 - sp0);
        logp -= 2.f * (0.6931471805599453f - a1v - sp1);
        out[b * 2 + 0] = tanhf(a0);
        out[b * 2 + 1] = tanhf(a1v);
        out[1024 + b] = logp;
    }
}

extern "C" void kernel_launch(void* const* d_in, const int* in_sizes, int n_in,
                              void* d_out, int out_size, void* d_ws, size_t ws_size,
                              hipStream_t stream) {
    const float* obs  = (const float*)d_in[0];
    const float* obst = (const float*)d_in[1];
    const float* eps  = (const float*)d_in[2];
    const float* W1   = (const float*)d_in[3];
    const float* b1   = (const float*)d_in[4];
    const float* W2   = (const float*)d_in[5];
    const float* b2   = (const float*)d_in[6];
    const float* muW  = (const float*)d_in[7];
    const float* mub  = (const float*)d_in[8];
    const float* lsW  = (const float*)d_in[9];
    const float* lsb  = (const float*)d_in[10];
    float* out = (float*)d_out;

    actor_kernel<<<512, 512, 0, stream>>>(obs, obst, eps, W1, b1, W2, b2,
                                          muW, mub, lsW, lsb, out);
}

// Round 13
// 31.082 us; speedup vs baseline: 1.8436x; 1.1374x over previous
//
#include <hip/hip_runtime.h>
#include <hip/hip_bf16.h>
#include <math.h>

typedef __attribute__((ext_vector_type(8))) short short8;
typedef __attribute__((ext_vector_type(4))) float f32x4;

__device__ __forceinline__ unsigned pkbf2(float lo, float hi) {
    __hip_bfloat162 h = __float22bfloat162_rn(make_float2(lo, hi));
    union { __hip_bfloat162 h; unsigned u; } c;
    c.h = h;
    return c.u;
}

// One fused kernel: 512 blocks (one per batch) x 512 threads (8 waves).
// Wave w owns output cols [w*32, w*32+32) (R8/R12 geometry, ~120 VGPR; the
// 64-col/wave variant needs 200+ arch regs and ALWAYS spills — R9/R10/R11).
// Double-buffered h1 slices (R12). New in R13: obstacle features (bf16-packed)
// and mask staged to LDS in the prologue — the steady loop has NO global-memory
// dependencies (R12 exposed ~900-cyc HBM mask loads before each slice barrier).
__global__ __launch_bounds__(512, 2) void actor_kernel(
    const float* __restrict__ obs,  const float* __restrict__ obst,
    const float* __restrict__ eps,  const float* __restrict__ W1,
    const float* __restrict__ b1,   const float* __restrict__ W2,
    const float* __restrict__ b2,   const float* __restrict__ muW,
    const float* __restrict__ mub,  const float* __restrict__ lsW,
    const float* __restrict__ lsb,  float* __restrict__ out)
{
    __shared__ __align__(16) short sA[2][4 * 64 * 64];  // 2 bufs x 32 KB
    __shared__ float sVeh[256];
    __shared__ __align__(8) unsigned sObstPk[256][2];   // bf16 pairs (o0,o1),(o2,o3)
    __shared__ float sMask[256];
    __shared__ float sRed[8][4];

    const int b = blockIdx.x;
    const int t = threadIdx.x;
    const int l = t & 63;
    const int w = t >> 6;          // wave: output cols [w*32, w*32+32)
    const int g = l >> 4;
    const int ln = l & 15;

    const float* ob = obst + b * 1280;

    // ---- prologue staging: threads 0-255 -> sVeh + sMask; 256-511 -> sObstPk ----
    if (t < 256) {
        float a = b1[t];
#pragma unroll
        for (int i = 0; i < 15; ++i) a = fmaf(obs[b * 15 + i], W1[i * 256 + t], a);
        sVeh[t] = a;
        sMask[t] = ob[1024 + t];
    } else {
        int n = t - 256;
        float o0 = ob[n], o1 = ob[256 + n], o2 = ob[512 + n], o3 = ob[768 + n];
        sObstPk[n][0] = pkbf2(o0, o1);
        sObstPk[n][1] = pkbf2(o2, o3);
    }

    // ---- layer-2 B-fragments from W2 (f32, row-major [k][col]) ----
    short8 bfr[8][2];
#pragma unroll
    for (int kt = 0; kt < 8; ++kt) {
#pragma unroll
        for (int c = 0; c < 2; ++c) {
            const float* p = W2 + (size_t)(kt * 32 + g * 8) * 256 + (w * 2 + c) * 16 + ln;
            union { short8 s; unsigned u[4]; } tv;
            tv.u[0] = pkbf2(p[0 * 256], p[1 * 256]);
            tv.u[1] = pkbf2(p[2 * 256], p[3 * 256]);
            tv.u[2] = pkbf2(p[4 * 256], p[5 * 256]);
            tv.u[3] = pkbf2(p[6 * 256], p[7 * 256]);
            bfr[kt][c] = tv.s;
        }
    }

    // ---- layer-1 A-fragments (W1obst^T, K=32 with only k<4 nonzero) ----
    short8 a1[2];
#pragma unroll
    for (int ji = 0; ji < 2; ++ji) {
        union { short8 s; unsigned u[4]; } tv;
        tv.u[0] = 0u; tv.u[1] = 0u; tv.u[2] = 0u; tv.u[3] = 0u;
        if (g == 0) {
            int j = (w * 2 + ji) * 16 + ln;
            tv.u[0] = pkbf2(W1[15 * 256 + j], W1[16 * 256 + j]);
            tv.u[1] = pkbf2(W1[17 * 256 + j], W1[18 * 256 + j]);
        }
        a1[ji] = tv.s;
    }

    // loop-invariant pooling weights for this lane's 2 cols
    float bb[2]; float2 mwv[2], lwv[2];
#pragma unroll
    for (int c = 0; c < 2; ++c) {
        int col = w * 32 + c * 16 + ln;
        bb[c] = b2[col];
        mwv[c] = *reinterpret_cast<const float2*>(muW + col * 2);
        lwv[c] = *reinterpret_cast<const float2*>(lsW + col * 2);
    }

    // layer-1 B-fragments for a slice, from LDS (lanes>=16 zero; a1 is zero there)
    short8 bf1[4];
    auto buildB1 = [&](int q) {
#pragma unroll
        for (int nt = 0; nt < 4; ++nt) {
            int n = q * 64 + nt * 16 + ln;
            uint2 o = *reinterpret_cast<const uint2*>(&sObstPk[n][0]);
            union { short8 s; unsigned u[4]; } tv;
            tv.u[0] = o.x; tv.u[1] = o.y; tv.u[2] = 0u; tv.u[3] = 0u;
            bf1[nt] = tv.s;
        }
    };

    // layer-1 of one 64-row slice -> sA[buf] (this wave's 2 j-tiles x 4 n-tiles)
    auto layer1 = [&](int buf) {
        char* base = (char*)&sA[buf][0];
#pragma unroll
        for (int ji = 0; ji < 2; ++ji) {
            int jt = w * 2 + ji;
            int j0 = jt * 16 + g * 4;
            f32x4 bias = *reinterpret_cast<const f32x4*>(&sVeh[j0]);
            unsigned page = (unsigned)(j0 >> 6) * 8192;
            unsigned jbyte = (unsigned)((j0 & 63) * 2);
#pragma unroll
            for (int nt = 0; nt < 4; ++nt) {
                f32x4 d = (f32x4){0.f, 0.f, 0.f, 0.f};
                d = __builtin_amdgcn_mfma_f32_16x16x32_bf16(a1[ji], bf1[nt], d, 0, 0, 0);
                int n = nt * 16 + ln;
                uint2 u;
                u.x = pkbf2(fmaxf(d[0] + bias[0], 0.f), fmaxf(d[1] + bias[1], 0.f));
                u.y = pkbf2(fmaxf(d[2] + bias[2], 0.f), fmaxf(d[3] + bias[3], 0.f));
                unsigned off = page + (unsigned)(n * 128) + (jbyte ^ ((unsigned)((n & 7) << 4)));
                *reinterpret_cast<uint2*>(base + off) = u;
            }
        }
    };

    f32x4 acc[4][2];
#pragma unroll
    for (int m = 0; m < 4; ++m)
#pragma unroll
        for (int c = 0; c < 2; ++c) acc[m][c] = (f32x4){0.f, 0.f, 0.f, 0.f};
    float m0 = 0.f, m1 = 0.f, s0 = 0.f, s1 = 0.f;

    __syncthreads();            // staging (sVeh, sObstPk, sMask) ready
    buildB1(0);
    layer1(0);                  // slice 0 -> buf 0
    __syncthreads();            // buf 0 ready

    for (int q = 0; q < 4; ++q) {
        int buf = q & 1;
        // ---- produce next slice into the other buffer (overlaps layer2 below) ----
        if (q < 3) { buildB1(q + 1); layer1(buf ^ 1); }

        // ---- layer 2: full K; B from registers, A from LDS buf ----
        const char* rbase = (const char*)&sA[buf][0];
#pragma unroll
        for (int kt = 0; kt < 8; ++kt) {
            unsigned page = (unsigned)(kt >> 1) * 8192;
            unsigned kbyte = (unsigned)((kt & 1) * 64 + g * 16);
#pragma unroll
            for (int m = 0; m < 4; ++m) {
                int n = m * 16 + ln;
                unsigned off = page + (unsigned)(n * 128) + (kbyte ^ ((unsigned)((n & 7) << 4)));
                short8 afr = *reinterpret_cast<const short8*>(rbase + off);
#pragma unroll
                for (int c = 0; c < 2; ++c)
                    acc[m][c] = __builtin_amdgcn_mfma_f32_16x16x32_bf16(afr, bfr[kt][c], acc[m][c], 0, 0, 0);
            }
        }

        // ---- masked pool of this slice (mask from LDS), fused muW/lsW dot ----
        const float* maskp = &sMask[q * 64];
#pragma unroll
        for (int c = 0; c < 2; ++c) {
            float p = 0.f;
#pragma unroll
            for (int m = 0; m < 4; ++m) {
                float4 M = *reinterpret_cast<const float4*>(maskp + m * 16 + g * 4);
                f32x4 v = acc[m][c];
                p = fmaf(M.x, fmaxf(v[0] + bb[c], 0.f), p);
                p = fmaf(M.y, fmaxf(v[1] + bb[c], 0.f), p);
                p = fmaf(M.z, fmaxf(v[2] + bb[c], 0.f), p);
                p = fmaf(M.w, fmaxf(v[3] + bb[c], 0.f), p);
                acc[m][c] = (f32x4){0.f, 0.f, 0.f, 0.f};
            }
            p += __shfl_xor(p, 16);
            p += __shfl_xor(p, 32);          // all lanes: pooled partial for col
            m0 = fmaf(p, mwv[c].x, m0);
            m1 = fmaf(p, mwv[c].y, m1);
            s0 = fmaf(p, lwv[c].x, s0);
            s1 = fmaf(p, lwv[c].y, s1);
        }
        if (q < 3) __syncthreads();          // next buf ready / reads drained
    }

    // ---- block-level reduction + head ----
#pragma unroll
    for (int off = 1; off < 16; off <<= 1) {
        m0 += __shfl_xor(m0, off);
        m1 += __shfl_xor(m1, off);
        s0 += __shfl_xor(s0, off);
        s1 += __shfl_xor(s1, off);
    }
    if (l == 0) { sRed[w][0] = m0; sRed[w][1] = m1; sRed[w][2] = s0; sRed[w][3] = s1; }
    __syncthreads();
    if (t == 0) {
        float M0 = 0.f, M1 = 0.f, S0 = 0.f, S1 = 0.f;
#pragma unroll
        for (int ww = 0; ww < 8; ++ww) {
            M0 += sRed[ww][0]; M1 += sRed[ww][1];
            S0 += sRed[ww][2]; S1 += sRed[ww][3];
        }
        float mu0 = M0 + mub[0], mu1 = M1 + mub[1];
        float ls0 = fminf(fmaxf(S0 + lsb[0], -20.f), 2.f);
        float ls1 = fminf(fmaxf(S1 + lsb[1], -20.f), 2.f);
        float e0 = eps[b * 2 + 0], e1 = eps[b * 2 + 1];
        float a0 = fmaf(expf(ls0), e0, mu0);
        float a1v = fmaf(expf(ls1), e1, mu1);
        float logp = -0.5f * (e0 * e0 + e1 * e1) - (ls0 + ls1) - 1.8378770664093453f;
        float x0 = -2.f * a0, x1 = -2.f * a1v;
        float sp0 = fmaxf(x0, 0.f) + log1pf(expf(-fabsf(x0)));
        float sp1 = fmaxf(x1, 0.f) + log1pf(expf(-fabsf(x1)));
        logp -= 2.f * (0.6931471805599453f - a0 - sp0);
        logp -= 2.f * (0.6931471805599453f - a1v - sp1);
        out[b * 2 + 0] = tanhf(a0);
        out[b * 2 + 1] = tanhf(a1v);
        out[1024 + b] = logp;
    }
}

extern "C" void kernel_launch(void* const* d_in, const int* in_sizes, int n_in,
                              void* d_out, int out_size, void* d_ws, size_t ws_size,
                              hipStream_t stream) {
    const float* obs  = (const float*)d_in[0];
    const float* obst = (const float*)d_in[1];
    const float* eps  = (const float*)d_in[2];
    const float* W1   = (const float*)d_in[3];
    const float* b1   = (const float*)d_in[4];
    const float* W2   = (const float*)d_in[5];
    const float* b2   = (const float*)d_in[6];
    const float* muW  = (const float*)d_in[7];
    const float* mub  = (const float*)d_in[8];
    const float* lsW  = (const float*)d_in[9];
    const float* lsb  = (const float*)d_in[10];
    float* out = (float*)d_out;

    actor_kernel<<<512, 512, 0, stream>>>(obs, obst, eps, W1, b1, W2, b2,
                                          muW, mub, lsW, lsb, out);
}